// Round 1
// baseline (1019.034 us; speedup 1.0000x reference)
//
#include <hip/hip_runtime.h>
#include <math.h>

#define NNODES 50000
#define NEDGES 800000
#define KIN 1024
#define DH 128

// ---------------- CSR build ----------------
__global__ void k_zero2(int* __restrict__ a, int* __restrict__ b, int n) {
  int i = blockIdx.x * blockDim.x + threadIdx.x;
  if (i < n) { a[i] = 0; b[i] = 0; }
}

__global__ void k_hist(const int* __restrict__ dst, int* __restrict__ cnt, int E) {
  int i = blockIdx.x * blockDim.x + threadIdx.x;
  if (i < E) atomicAdd(&cnt[dst[i]], 1);
}

// single-block exclusive scan over n counts -> row_ptr[0..n]
__global__ void k_scan(const int* __restrict__ cnt, int* __restrict__ row_ptr, int n) {
  __shared__ int sdata[1024];
  __shared__ int carry;
  int t = threadIdx.x;
  if (t == 0) carry = 0;
  __syncthreads();
  for (int base = 0; base < n; base += 1024) {
    int i = base + t;
    int v = (i < n) ? cnt[i] : 0;
    sdata[t] = v;
    __syncthreads();
    for (int off = 1; off < 1024; off <<= 1) {
      int tv = (t >= off) ? sdata[t - off] : 0;
      __syncthreads();
      sdata[t] += tv;
      __syncthreads();
    }
    int incl = sdata[t];
    int c0 = carry;
    if (i < n) row_ptr[i] = c0 + incl - v;
    __syncthreads();
    if (t == 1023) carry = c0 + incl;
    __syncthreads();
  }
  if (t == 0) row_ptr[n] = carry;
}

__global__ void k_fill(const int* __restrict__ src, const int* __restrict__ dst,
                       const int* __restrict__ row_ptr, int* __restrict__ cursor,
                       int* __restrict__ csr_src, int E) {
  int i = blockIdx.x * blockDim.x + threadIdx.x;
  if (i < E) {
    int d = dst[i];
    int pos = row_ptr[d] + atomicAdd(&cursor[d], 1);
    csr_src[pos] = src[i];
  }
}

// ---------------- fused GEMM: XW = X@W ; RES = relu(X@Wr + br) ----------------
// BM=128 rows x BN=256 cols (cols 0..127 -> W, 128..255 -> Wr), BK=32, 512 threads,
// 8x8 per-thread tile.
#define BM 128
#define BN 256
#define BK 32
#define ASTR 132  // padded LDS stride for transposed A tile

__global__ __launch_bounds__(512) void k_gemm(
    const float* __restrict__ X, const float* __restrict__ W,
    const float* __restrict__ Wr, const float* __restrict__ br,
    float* __restrict__ XW, float* __restrict__ RES, int M, int K) {
  __shared__ float As[BK * ASTR];  // [k][m], padded
  __shared__ float Bs[BK * BN];    // [k][n]
  const int tid = threadIdx.x;
  const int tx = tid & 31;   // col group: cols 8*tx .. 8*tx+7
  const int ty = tid >> 5;   // row group: rows 8*ty .. 8*ty+7
  const int bm0 = blockIdx.x * BM;

  float acc[8][8];
#pragma unroll
  for (int i = 0; i < 8; ++i)
#pragma unroll
    for (int j = 0; j < 8; ++j) acc[i][j] = 0.f;

  for (int k0 = 0; k0 < K; k0 += BK) {
    // stage A tile (128x32), transposed into As[k][m]
#pragma unroll
    for (int l = 0; l < 2; ++l) {
      int q = tid + l * 512;       // 0..1023 float4 slots
      int row = q >> 3;            // 0..127
      int c4 = (q & 7) << 2;       // k offset 0..28
      int grow = bm0 + row; if (grow > M - 1) grow = M - 1;
      const float4 v = *(const float4*)&X[(size_t)grow * K + k0 + c4];
      As[(c4 + 0) * ASTR + row] = v.x;
      As[(c4 + 1) * ASTR + row] = v.y;
      As[(c4 + 2) * ASTR + row] = v.z;
      As[(c4 + 3) * ASTR + row] = v.w;
    }
    // stage B tile (32x256): left half from W, right half from Wr
#pragma unroll
    for (int l = 0; l < 4; ++l) {
      int q = tid + l * 512;       // 0..2047 float4 slots
      int krow = q >> 6;           // 0..31
      int col = (q & 63) << 2;     // 0..252
      const float* bsrc = (col < DH) ? (W + (size_t)(k0 + krow) * DH + col)
                                     : (Wr + (size_t)(k0 + krow) * DH + (col - DH));
      *(float4*)&Bs[krow * BN + col] = *(const float4*)bsrc;
    }
    __syncthreads();
#pragma unroll 8
    for (int kk = 0; kk < BK; ++kk) {
      const float4 a0 = *(const float4*)&As[kk * ASTR + (ty << 3)];
      const float4 a1 = *(const float4*)&As[kk * ASTR + (ty << 3) + 4];
      const float4 b0 = *(const float4*)&Bs[kk * BN + (tx << 3)];
      const float4 b1 = *(const float4*)&Bs[kk * BN + (tx << 3) + 4];
      const float av[8] = {a0.x, a0.y, a0.z, a0.w, a1.x, a1.y, a1.z, a1.w};
      const float bv[8] = {b0.x, b0.y, b0.z, b0.w, b1.x, b1.y, b1.z, b1.w};
#pragma unroll
      for (int i = 0; i < 8; ++i)
#pragma unroll
        for (int j = 0; j < 8; ++j)
          acc[i][j] = fmaf(av[i], bv[j], acc[i][j]);
    }
    __syncthreads();
  }

  const int cb = tx << 3;
  if (cb < DH) {
#pragma unroll
    for (int i = 0; i < 8; ++i) {
      int gm = bm0 + (ty << 3) + i;
      if (gm < M) {
        *(float4*)&XW[(size_t)gm * DH + cb] =
            make_float4(acc[i][0], acc[i][1], acc[i][2], acc[i][3]);
        *(float4*)&XW[(size_t)gm * DH + cb + 4] =
            make_float4(acc[i][4], acc[i][5], acc[i][6], acc[i][7]);
      }
    }
  } else {
    const int c = cb - DH;
    float brv[8];
#pragma unroll
    for (int j = 0; j < 8; ++j) brv[j] = br[c + j];
#pragma unroll
    for (int i = 0; i < 8; ++i) {
      int gm = bm0 + (ty << 3) + i;
      if (gm < M) {
        *(float4*)&RES[(size_t)gm * DH + c] =
            make_float4(fmaxf(acc[i][0] + brv[0], 0.f), fmaxf(acc[i][1] + brv[1], 0.f),
                        fmaxf(acc[i][2] + brv[2], 0.f), fmaxf(acc[i][3] + brv[3], 0.f));
        *(float4*)&RES[(size_t)gm * DH + c + 4] =
            make_float4(fmaxf(acc[i][4] + brv[4], 0.f), fmaxf(acc[i][5] + brv[5], 0.f),
                        fmaxf(acc[i][6] + brv[6], 0.f), fmaxf(acc[i][7] + brv[7], 0.f));
      }
    }
  }
}

// ---------------- aggregation + bias + relu + residual + BN ----------------
// 2 nodes per 256-thread block; thread f handles one feature of one node.
// RES and hout may alias (per-element in-place), so no __restrict__ on them.
__global__ __launch_bounds__(256) void k_agg(
    const float* __restrict__ XW, const float* RES,
    const int* __restrict__ row_ptr, const int* __restrict__ csr_src,
    const float* __restrict__ b, const float* __restrict__ gamma,
    const float* __restrict__ beta, const float* __restrict__ mean,
    const float* __restrict__ var, float* hout, int M) {
  int node = (blockIdx.x << 1) + (threadIdx.x >> 7);
  int f = threadIdx.x & 127;
  if (node >= M) return;
  int s = row_ptr[node], e = row_ptr[node + 1];
  float acc = 0.f;
  int i = s;
  for (; i + 1 < e; i += 2) {
    int s0 = csr_src[i], s1 = csr_src[i + 1];
    float v0 = XW[(size_t)s0 * DH + f];
    float v1 = XW[(size_t)s1 * DH + f];
    acc += v0 + v1;
  }
  if (i < e) acc += XW[(size_t)csr_src[i] * DH + f];
  float x = fmaxf(acc + b[f], 0.f) + RES[(size_t)node * DH + f];
  float y = (x - mean[f]) * rsqrtf(var[f] + 1e-5f) * gamma[f] + beta[f];
  hout[(size_t)node * DH + f] = y;
}

// ---------------- head: logits = h@Wd + bd ; softmax ----------------
// one wave (64 lanes) per node; each lane covers 2 of the 128 features.
__global__ __launch_bounds__(256) void k_head(const float* __restrict__ h,
                                              const float* __restrict__ Wd,
                                              const float* __restrict__ bd,
                                              float* __restrict__ out, int M) {
  int wid = (blockIdx.x * blockDim.x + threadIdx.x) >> 6;
  int lane = threadIdx.x & 63;
  if (wid >= M) return;
  const float* hr = h + (size_t)wid * DH;
  int k0 = lane * 2;
  float2 hv = *(const float2*)&hr[k0];
  float2 w0 = *(const float2*)&Wd[k0 * 2];        // (Wd[k0][0], Wd[k0][1])
  float2 w1 = *(const float2*)&Wd[(k0 + 1) * 2];  // (Wd[k0+1][0], Wd[k0+1][1])
  float l0 = hv.x * w0.x + hv.y * w1.x;
  float l1 = hv.x * w0.y + hv.y * w1.y;
#pragma unroll
  for (int off = 32; off > 0; off >>= 1) {
    l0 += __shfl_down(l0, off);
    l1 += __shfl_down(l1, off);
  }
  if (lane == 0) {
    l0 += bd[0];
    l1 += bd[1];
    float m = fmaxf(l0, l1);
    float e0 = expf(l0 - m), e1 = expf(l1 - m);
    float inv = 1.f / (e0 + e1);
    out[(size_t)wid * 2] = e0 * inv;
    out[(size_t)wid * 2 + 1] = e1 * inv;
  }
}

// ---------------- launch ----------------
extern "C" void kernel_launch(void* const* d_in, const int* in_sizes, int n_in,
                              void* d_out, int out_size, void* d_ws, size_t ws_size,
                              hipStream_t stream) {
  const float* in_feat = (const float*)d_in[0];
  const int* src = (const int*)d_in[1];
  const int* dst = (const int*)d_in[2];
  const float* W0 = (const float*)d_in[3];
  const float* b0 = (const float*)d_in[4];
  const float* Wr0 = (const float*)d_in[5];
  const float* br0 = (const float*)d_in[6];
  const float* gamma0 = (const float*)d_in[7];
  const float* beta0 = (const float*)d_in[8];
  const float* mean0 = (const float*)d_in[9];
  const float* var0 = (const float*)d_in[10];
  const float* W1 = (const float*)d_in[11];
  const float* b1 = (const float*)d_in[12];
  const float* Wr1 = (const float*)d_in[13];
  const float* br1 = (const float*)d_in[14];
  const float* gamma1 = (const float*)d_in[15];
  const float* beta1 = (const float*)d_in[16];
  const float* mean1 = (const float*)d_in[17];
  const float* var1 = (const float*)d_in[18];
  const float* Wd = (const float*)d_in[19];
  const float* bd = (const float*)d_in[20];
  float* out = (float*)d_out;

  // workspace layout (~80.4 MB total)
  char* ws = (char*)d_ws;
  size_t off = 0;
  auto alloc = [&](size_t bytes) {
    void* p = ws + off;
    off += (bytes + 255) & ~(size_t)255;
    return p;
  };
  float* buf1 = (float*)alloc(sizeof(float) * (size_t)NNODES * DH);  // XW
  float* buf2 = (float*)alloc(sizeof(float) * (size_t)NNODES * DH);  // RES0 / h1
  float* buf3 = (float*)alloc(sizeof(float) * (size_t)NNODES * DH);  // RES1 / h2
  int* cnt = (int*)alloc(sizeof(int) * NNODES);
  int* cursor = (int*)alloc(sizeof(int) * NNODES);
  int* row_ptr = (int*)alloc(sizeof(int) * (NNODES + 1));
  int* csr_src = (int*)alloc(sizeof(int) * NEDGES);

  // CSR build (dst is identical for both layers)
  k_zero2<<<(NNODES + 255) / 256, 256, 0, stream>>>(cnt, cursor, NNODES);
  k_hist<<<(NEDGES + 255) / 256, 256, 0, stream>>>(dst, cnt, NEDGES);
  k_scan<<<1, 1024, 0, stream>>>(cnt, row_ptr, NNODES);
  k_fill<<<(NEDGES + 255) / 256, 256, 0, stream>>>(src, dst, row_ptr, cursor, csr_src, NEDGES);

  const int gemm_grid = (NNODES + BM - 1) / BM;
  // layer 0
  k_gemm<<<gemm_grid, 512, 0, stream>>>(in_feat, W0, Wr0, br0, buf1, buf2, NNODES, KIN);
  k_agg<<<(NNODES + 1) / 2, 256, 0, stream>>>(buf1, buf2, row_ptr, csr_src, b0, gamma0,
                                              beta0, mean0, var0, buf2, NNODES);
  // layer 1
  k_gemm<<<gemm_grid, 512, 0, stream>>>(buf2, W1, Wr1, br1, buf1, buf3, NNODES, DH);
  k_agg<<<(NNODES + 1) / 2, 256, 0, stream>>>(buf1, buf3, row_ptr, csr_src, b1, gamma1,
                                              beta1, mean1, var1, buf3, NNODES);
  // head
  k_head<<<(NNODES + 3) / 4, 256, 0, stream>>>(buf3, Wd, bd, out, NNODES);
}

// Round 2
// 793.134 us; speedup vs baseline: 1.2848x; 1.2848x over previous
//
#include <hip/hip_runtime.h>
#include <math.h>

#define NNODES 50000
#define NEDGES 800000
#define KIN 1024
#define DH 128

typedef __bf16 bf16x8 __attribute__((ext_vector_type(8)));
typedef float floatx4 __attribute__((ext_vector_type(4)));

// ---------------- CSR build ----------------
__global__ void k_zero2(int* __restrict__ a, int* __restrict__ b, int n) {
  int i = blockIdx.x * blockDim.x + threadIdx.x;
  if (i < n) { a[i] = 0; b[i] = 0; }
}

__global__ void k_hist(const int* __restrict__ dst, int* __restrict__ cnt, int E) {
  int i = blockIdx.x * blockDim.x + threadIdx.x;
  if (i < E) atomicAdd(&cnt[dst[i]], 1);
}

// single-block exclusive scan over n counts -> row_ptr[0..n]
__global__ void k_scan(const int* __restrict__ cnt, int* __restrict__ row_ptr, int n) {
  __shared__ int sdata[1024];
  __shared__ int carry;
  int t = threadIdx.x;
  if (t == 0) carry = 0;
  __syncthreads();
  for (int base = 0; base < n; base += 1024) {
    int i = base + t;
    int v = (i < n) ? cnt[i] : 0;
    sdata[t] = v;
    __syncthreads();
    for (int off = 1; off < 1024; off <<= 1) {
      int tv = (t >= off) ? sdata[t - off] : 0;
      __syncthreads();
      sdata[t] += tv;
      __syncthreads();
    }
    int incl = sdata[t];
    int c0 = carry;
    if (i < n) row_ptr[i] = c0 + incl - v;
    __syncthreads();
    if (t == 1023) carry = c0 + incl;
    __syncthreads();
  }
  if (t == 0) row_ptr[n] = carry;
}

__global__ void k_fill(const int* __restrict__ src, const int* __restrict__ dst,
                       const int* __restrict__ row_ptr, int* __restrict__ cursor,
                       int* __restrict__ csr_src, int E) {
  int i = blockIdx.x * blockDim.x + threadIdx.x;
  if (i < E) {
    int d = dst[i];
    int pos = row_ptr[d] + atomicAdd(&cursor[d], 1);
    csr_src[pos] = src[i];
  }
}

// ---------------- B pre-convert: Bt[256][1024] bf16, Bt[n][k] = (W|Wr)[k][n] ----------------
__global__ __launch_bounds__(256) void k_prepB(const float* __restrict__ W,
                                               const float* __restrict__ Wr,
                                               __bf16* __restrict__ Bt, int K) {
  int id = blockIdx.x * blockDim.x + threadIdx.x;  // K*256 total
  int k = id & (K - 1);
  int n = id >> 10;  // K==1024
  float v = (n < DH) ? W[(size_t)k * DH + n] : Wr[(size_t)k * DH + (n - DH)];
  Bt[(size_t)n * K + k] = (__bf16)v;
}

// ---------------- layer-0 GEMM, bf16 MFMA ----------------
// BM=64 rows x BN=256 cols (0..127 -> XW, 128..255 -> RES), BK=32.
// 256 threads = 4 waves; wave w covers all 64 rows x cols [w*64, w*64+64).
// A (f32) converted to bf16 during LDS staging; B staged from pre-converted
// bf16 Bt[256][1024] via global_load_lds (XOR-swizzled chunks).
#define ASTR 40  // bf16 elems per As row (80 B, 16B-aligned, conflict-free)

__device__ __forceinline__ void load_lds16(const void* g, void* l) {
  __builtin_amdgcn_global_load_lds(
      (const __attribute__((address_space(1))) unsigned int*)g,
      (__attribute__((address_space(3))) unsigned int*)l, 16, 0, 0);
}

__global__ __launch_bounds__(256, 3) void k_gemm0_mfma(
    const float* __restrict__ X, const __bf16* __restrict__ Bt,
    const float* __restrict__ br, float* __restrict__ XW,
    float* __restrict__ RES, int M) {
  __shared__ alignas(16) __bf16 As[64 * ASTR];
  __shared__ alignas(16) __bf16 Bs[256 * 32];
  const int tid = threadIdx.x;
  const int lane = tid & 63;
  const int w = tid >> 6;        // wave 0..3
  const int l15 = lane & 15;
  const int quad = lane >> 4;    // 0..3
  const int bm0 = blockIdx.x * 64;

  // A staging mapping: thread t -> row t>>2, k-chunk (t&3)*8
  const int arow = tid >> 2;
  const int akq = (tid & 3) << 3;
  int agrow = bm0 + arow; if (agrow > M - 1) agrow = M - 1;
  const float* aptr = X + (size_t)agrow * KIN + akq;

  floatx4 acc[4][4];
#pragma unroll
  for (int i = 0; i < 4; ++i)
#pragma unroll
    for (int j = 0; j < 4; ++j) acc[i][j] = (floatx4)0.f;

  for (int k0 = 0; k0 < KIN; k0 += 32) {
    // --- stage A: 64x32 f32 -> bf16 ---
    {
      const float4 u = *(const float4*)(aptr + k0);
      const float4 v = *(const float4*)(aptr + k0 + 4);
      bf16x8 h;
      h[0] = (__bf16)u.x; h[1] = (__bf16)u.y; h[2] = (__bf16)u.z; h[3] = (__bf16)u.w;
      h[4] = (__bf16)v.x; h[5] = (__bf16)v.y; h[6] = (__bf16)v.z; h[7] = (__bf16)v.w;
      *(bf16x8*)&As[arow * ASTR + akq] = h;
    }
    // --- stage B: 256x32 bf16 via global_load_lds, XOR swizzle ---
#pragma unroll
    for (int i = 0; i < 4; ++i) {
      const int wi = i * 4 + w;                    // wave-issue 0..15
      const int f = wi * 1024 + lane * 16;         // flat LDS byte offset
      const int n = f >> 6;                        // 0..255
      const int c = (f >> 4) & 3;                  // dst chunk
      const int cs = c ^ (n & 3);                  // src k-chunk (swizzle)
      const char* g = (const char*)Bt + (size_t)n * (KIN * 2) + k0 * 2 + cs * 16;
      load_lds16(g, (char*)Bs + wi * 1024);
    }
    __syncthreads();
    // --- fragments + MFMA ---
    bf16x8 af[4], bf[4];
#pragma unroll
    for (int mt = 0; mt < 4; ++mt)
      af[mt] = *(const bf16x8*)&As[(mt * 16 + l15) * ASTR + quad * 8];
#pragma unroll
    for (int nt = 0; nt < 4; ++nt) {
      const int n = w * 64 + nt * 16 + l15;
      bf[nt] = *(const bf16x8*)&Bs[n * 32 + (quad ^ (n & 3)) * 8];
    }
#pragma unroll
    for (int mt = 0; mt < 4; ++mt)
#pragma unroll
      for (int nt = 0; nt < 4; ++nt)
        acc[mt][nt] = __builtin_amdgcn_mfma_f32_16x16x32_bf16(af[mt], bf[nt],
                                                              acc[mt][nt], 0, 0, 0);
    __syncthreads();
  }

  // --- epilogue: C/D layout col=lane&15, row=quad*4+r ---
  const int colbase = w * 64;
  if (colbase < DH) {
#pragma unroll
    for (int nt = 0; nt < 4; ++nt) {
      const int n = colbase + nt * 16 + l15;
#pragma unroll
      for (int mt = 0; mt < 4; ++mt) {
#pragma unroll
        for (int r = 0; r < 4; ++r) {
          const int m = bm0 + mt * 16 + quad * 4 + r;
          if (m < M) XW[(size_t)m * DH + n] = acc[mt][nt][r];
        }
      }
    }
  } else {
#pragma unroll
    for (int nt = 0; nt < 4; ++nt) {
      const int n = colbase + nt * 16 + l15;
      const float bb = br[n - DH];
#pragma unroll
      for (int mt = 0; mt < 4; ++mt) {
#pragma unroll
        for (int r = 0; r < 4; ++r) {
          const int m = bm0 + mt * 16 + quad * 4 + r;
          if (m < M) RES[(size_t)m * DH + (n - DH)] = fmaxf(acc[mt][nt][r] + bb, 0.f);
        }
      }
    }
  }
}

// ---------------- layer-1 fused GEMM (f32 VALU): XW = X@W ; RES = relu(X@Wr + br) ----------------
#define BM 128
#define BN 256
#define BK 32
#define FASTR 132

__global__ __launch_bounds__(512) void k_gemm(
    const float* __restrict__ X, const float* __restrict__ W,
    const float* __restrict__ Wr, const float* __restrict__ br,
    float* __restrict__ XW, float* __restrict__ RES, int M, int K) {
  __shared__ float As[BK * FASTR];  // [k][m], padded
  __shared__ float Bs[BK * BN];     // [k][n]
  const int tid = threadIdx.x;
  const int tx = tid & 31;
  const int ty = tid >> 5;
  const int bm0 = blockIdx.x * BM;

  float acc[8][8];
#pragma unroll
  for (int i = 0; i < 8; ++i)
#pragma unroll
    for (int j = 0; j < 8; ++j) acc[i][j] = 0.f;

  for (int k0 = 0; k0 < K; k0 += BK) {
#pragma unroll
    for (int l = 0; l < 2; ++l) {
      int q = tid + l * 512;
      int row = q >> 3;
      int c4 = (q & 7) << 2;
      int grow = bm0 + row; if (grow > M - 1) grow = M - 1;
      const float4 v = *(const float4*)&X[(size_t)grow * K + k0 + c4];
      As[(c4 + 0) * FASTR + row] = v.x;
      As[(c4 + 1) * FASTR + row] = v.y;
      As[(c4 + 2) * FASTR + row] = v.z;
      As[(c4 + 3) * FASTR + row] = v.w;
    }
#pragma unroll
    for (int l = 0; l < 4; ++l) {
      int q = tid + l * 512;
      int krow = q >> 6;
      int col = (q & 63) << 2;
      const float* bsrc = (col < DH) ? (W + (size_t)(k0 + krow) * DH + col)
                                     : (Wr + (size_t)(k0 + krow) * DH + (col - DH));
      *(float4*)&Bs[krow * BN + col] = *(const float4*)bsrc;
    }
    __syncthreads();
#pragma unroll 8
    for (int kk = 0; kk < BK; ++kk) {
      const float4 a0 = *(const float4*)&As[kk * FASTR + (ty << 3)];
      const float4 a1 = *(const float4*)&As[kk * FASTR + (ty << 3) + 4];
      const float4 b0 = *(const float4*)&Bs[kk * BN + (tx << 3)];
      const float4 b1 = *(const float4*)&Bs[kk * BN + (tx << 3) + 4];
      const float av[8] = {a0.x, a0.y, a0.z, a0.w, a1.x, a1.y, a1.z, a1.w};
      const float bv[8] = {b0.x, b0.y, b0.z, b0.w, b1.x, b1.y, b1.z, b1.w};
#pragma unroll
      for (int i = 0; i < 8; ++i)
#pragma unroll
        for (int j = 0; j < 8; ++j)
          acc[i][j] = fmaf(av[i], bv[j], acc[i][j]);
    }
    __syncthreads();
  }

  const int cb = tx << 3;
  if (cb < DH) {
#pragma unroll
    for (int i = 0; i < 8; ++i) {
      int gm = bm0 + (ty << 3) + i;
      if (gm < M) {
        *(float4*)&XW[(size_t)gm * DH + cb] =
            make_float4(acc[i][0], acc[i][1], acc[i][2], acc[i][3]);
        *(float4*)&XW[(size_t)gm * DH + cb + 4] =
            make_float4(acc[i][4], acc[i][5], acc[i][6], acc[i][7]);
      }
    }
  } else {
    const int c = cb - DH;
    float brv[8];
#pragma unroll
    for (int j = 0; j < 8; ++j) brv[j] = br[c + j];
#pragma unroll
    for (int i = 0; i < 8; ++i) {
      int gm = bm0 + (ty << 3) + i;
      if (gm < M) {
        *(float4*)&RES[(size_t)gm * DH + c] =
            make_float4(fmaxf(acc[i][0] + brv[0], 0.f), fmaxf(acc[i][1] + brv[1], 0.f),
                        fmaxf(acc[i][2] + brv[2], 0.f), fmaxf(acc[i][3] + brv[3], 0.f));
        *(float4*)&RES[(size_t)gm * DH + c + 4] =
            make_float4(fmaxf(acc[i][4] + brv[4], 0.f), fmaxf(acc[i][5] + brv[5], 0.f),
                        fmaxf(acc[i][6] + brv[6], 0.f), fmaxf(acc[i][7] + brv[7], 0.f));
      }
    }
  }
}

// ---------------- aggregation + bias + relu + residual + BN ----------------
__global__ __launch_bounds__(256) void k_agg(
    const float* __restrict__ XW, const float* RES,
    const int* __restrict__ row_ptr, const int* __restrict__ csr_src,
    const float* __restrict__ b, const float* __restrict__ gamma,
    const float* __restrict__ beta, const float* __restrict__ mean,
    const float* __restrict__ var, float* hout, int M) {
  int node = (blockIdx.x << 1) + (threadIdx.x >> 7);
  int f = threadIdx.x & 127;
  if (node >= M) return;
  int s = row_ptr[node], e = row_ptr[node + 1];
  float acc = 0.f;
  int i = s;
  for (; i + 1 < e; i += 2) {
    int s0 = csr_src[i], s1 = csr_src[i + 1];
    float v0 = XW[(size_t)s0 * DH + f];
    float v1 = XW[(size_t)s1 * DH + f];
    acc += v0 + v1;
  }
  if (i < e) acc += XW[(size_t)csr_src[i] * DH + f];
  float x = fmaxf(acc + b[f], 0.f) + RES[(size_t)node * DH + f];
  float y = (x - mean[f]) * rsqrtf(var[f] + 1e-5f) * gamma[f] + beta[f];
  hout[(size_t)node * DH + f] = y;
}

// ---------------- head: logits = h@Wd + bd ; softmax ----------------
__global__ __launch_bounds__(256) void k_head(const float* __restrict__ h,
                                              const float* __restrict__ Wd,
                                              const float* __restrict__ bd,
                                              float* __restrict__ out, int M) {
  int wid = (blockIdx.x * blockDim.x + threadIdx.x) >> 6;
  int lane = threadIdx.x & 63;
  if (wid >= M) return;
  const float* hr = h + (size_t)wid * DH;
  int k0 = lane * 2;
  float2 hv = *(const float2*)&hr[k0];
  float2 w0 = *(const float2*)&Wd[k0 * 2];
  float2 w1 = *(const float2*)&Wd[(k0 + 1) * 2];
  float l0 = hv.x * w0.x + hv.y * w1.x;
  float l1 = hv.x * w0.y + hv.y * w1.y;
#pragma unroll
  for (int off = 32; off > 0; off >>= 1) {
    l0 += __shfl_down(l0, off);
    l1 += __shfl_down(l1, off);
  }
  if (lane == 0) {
    l0 += bd[0];
    l1 += bd[1];
    float m = fmaxf(l0, l1);
    float e0 = expf(l0 - m), e1 = expf(l1 - m);
    float inv = 1.f / (e0 + e1);
    out[(size_t)wid * 2] = e0 * inv;
    out[(size_t)wid * 2 + 1] = e1 * inv;
  }
}

// ---------------- launch ----------------
extern "C" void kernel_launch(void* const* d_in, const int* in_sizes, int n_in,
                              void* d_out, int out_size, void* d_ws, size_t ws_size,
                              hipStream_t stream) {
  const float* in_feat = (const float*)d_in[0];
  const int* src = (const int*)d_in[1];
  const int* dst = (const int*)d_in[2];
  const float* W0 = (const float*)d_in[3];
  const float* b0 = (const float*)d_in[4];
  const float* Wr0 = (const float*)d_in[5];
  const float* br0 = (const float*)d_in[6];
  const float* gamma0 = (const float*)d_in[7];
  const float* beta0 = (const float*)d_in[8];
  const float* mean0 = (const float*)d_in[9];
  const float* var0 = (const float*)d_in[10];
  const float* W1 = (const float*)d_in[11];
  const float* b1 = (const float*)d_in[12];
  const float* Wr1 = (const float*)d_in[13];
  const float* br1 = (const float*)d_in[14];
  const float* gamma1 = (const float*)d_in[15];
  const float* beta1 = (const float*)d_in[16];
  const float* mean1 = (const float*)d_in[17];
  const float* var1 = (const float*)d_in[18];
  const float* Wd = (const float*)d_in[19];
  const float* bd = (const float*)d_in[20];
  float* out = (float*)d_out;

  char* ws = (char*)d_ws;
  size_t off = 0;
  auto alloc = [&](size_t bytes) {
    void* p = ws + off;
    off += (bytes + 255) & ~(size_t)255;
    return p;
  };
  float* buf1 = (float*)alloc(sizeof(float) * (size_t)NNODES * DH);  // XW
  float* buf2 = (float*)alloc(sizeof(float) * (size_t)NNODES * DH);  // RES0 / h1
  float* buf3 = (float*)alloc(sizeof(float) * (size_t)NNODES * DH);  // RES1 / h2
  int* cnt = (int*)alloc(sizeof(int) * NNODES);
  int* cursor = (int*)alloc(sizeof(int) * NNODES);
  int* row_ptr = (int*)alloc(sizeof(int) * (NNODES + 1));
  int* csr_src = (int*)alloc(sizeof(int) * NEDGES);
  __bf16* Bt0 = (__bf16*)alloc(sizeof(__bf16) * 256 * KIN);  // [256][1024]

  // CSR build (dst is identical for both layers)
  k_zero2<<<(NNODES + 255) / 256, 256, 0, stream>>>(cnt, cursor, NNODES);
  k_hist<<<(NEDGES + 255) / 256, 256, 0, stream>>>(dst, cnt, NEDGES);
  k_scan<<<1, 1024, 0, stream>>>(cnt, row_ptr, NNODES);
  k_fill<<<(NEDGES + 255) / 256, 256, 0, stream>>>(src, dst, row_ptr, cursor, csr_src, NEDGES);

  // layer 0 (bf16 MFMA)
  k_prepB<<<(256 * KIN) / 256, 256, 0, stream>>>(W0, Wr0, Bt0, KIN);
  k_gemm0_mfma<<<(NNODES + 63) / 64, 256, 0, stream>>>(in_feat, Bt0, br0, buf1, buf2, NNODES);
  k_agg<<<(NNODES + 1) / 2, 256, 0, stream>>>(buf1, buf2, row_ptr, csr_src, b0, gamma0,
                                              beta0, mean0, var0, buf2, NNODES);
  // layer 1 (f32)
  k_gemm<<<(NNODES + BM - 1) / BM, 512, 0, stream>>>(buf2, W1, Wr1, br1, buf1, buf3, NNODES, DH);
  k_agg<<<(NNODES + 1) / 2, 256, 0, stream>>>(buf1, buf3, row_ptr, csr_src, b1, gamma1,
                                              beta1, mean1, var1, buf3, NNODES);
  // head
  k_head<<<(NNODES + 3) / 4, 256, 0, stream>>>(buf3, Wd, bd, out, NNODES);
}

// Round 3
// 556.165 us; speedup vs baseline: 1.8323x; 1.4261x over previous
//
#include <hip/hip_runtime.h>
#include <math.h>

#define NNODES 50000
#define NEDGES 800000
#define KIN 1024
#define DH 128

typedef __bf16 bf16x8 __attribute__((ext_vector_type(8)));
typedef float floatx4 __attribute__((ext_vector_type(4)));

// ---------------- CSR build ----------------
__global__ void k_zero2(int* __restrict__ a, int* __restrict__ b, int n) {
  int i = blockIdx.x * blockDim.x + threadIdx.x;
  if (i < n) { a[i] = 0; b[i] = 0; }
}

__global__ void k_hist(const int* __restrict__ dst, int* __restrict__ cnt, int E) {
  int i = blockIdx.x * blockDim.x + threadIdx.x;
  if (i < E) atomicAdd(&cnt[dst[i]], 1);
}

// hierarchical scan: per-block 1024-elem scan + block sums
__global__ __launch_bounds__(1024) void k_scan_local(const int* __restrict__ cnt,
                                                     int* __restrict__ row_ptr,
                                                     int* __restrict__ bsum, int n) {
  __shared__ int sd[1024];
  int t = threadIdx.x;
  int i = blockIdx.x * 1024 + t;
  int v = (i < n) ? cnt[i] : 0;
  sd[t] = v;
  __syncthreads();
  for (int off = 1; off < 1024; off <<= 1) {
    int tv = (t >= off) ? sd[t - off] : 0;
    __syncthreads();
    sd[t] += tv;
    __syncthreads();
  }
  if (i < n) row_ptr[i] = sd[t] - v;  // exclusive within block
  if (t == 1023) bsum[blockIdx.x] = sd[t];
}

// one wave scans the <=64 block sums; writes exclusive offsets + grand total
__global__ void k_scan_sums(const int* __restrict__ bsum, int* __restrict__ boff,
                            int nb, int* __restrict__ row_ptr, int n) {
  int lane = threadIdx.x;  // 64 threads
  int v = (lane < nb) ? bsum[lane] : 0;
  int incl = v;
  for (int off = 1; off < 64; off <<= 1) {
    int t = __shfl_up(incl, off);
    if (lane >= off) incl += t;
  }
  boff[lane] = incl - v;
  if (lane == 63) row_ptr[n] = incl;
}

__global__ void k_scan_add(int* __restrict__ row_ptr, const int* __restrict__ boff, int n) {
  int i = blockIdx.x * blockDim.x + threadIdx.x;
  if (i < n) row_ptr[i] += boff[i >> 10];
}

__global__ void k_fill(const int* __restrict__ src, const int* __restrict__ dst,
                       const int* __restrict__ row_ptr, int* __restrict__ cursor,
                       int* __restrict__ csr_src, int E) {
  int i = blockIdx.x * blockDim.x + threadIdx.x;
  if (i < E) {
    int d = dst[i];
    int pos = row_ptr[d] + atomicAdd(&cursor[d], 1);
    csr_src[pos] = src[i];
  }
}

// ---------------- B pre-convert: Bt[256][K] bf16, Bt[n][k] = (W|Wr)[k][n] ----------------
__global__ __launch_bounds__(256) void k_prepB(const float* __restrict__ W,
                                               const float* __restrict__ Wr,
                                               __bf16* __restrict__ Bt, int K, int kbits) {
  int id = blockIdx.x * 256 + threadIdx.x;  // 256*K total
  int k = id & (K - 1);
  int n = id >> kbits;
  float v = (n < DH) ? W[(size_t)k * DH + n] : Wr[(size_t)k * DH + (n - DH)];
  Bt[(size_t)n * K + k] = (__bf16)v;
}

// ---------------- MFMA GEMM: XW(bf16) = X@W ; RES(f32) = relu(X@Wr + br) ----------------
// BM=32 x BN=256 (cols 0..127 -> XW, 128..255 -> RES), BK=64, 256 thr = 4 waves.
// Wave w: 32 rows x cols [w*64, w*64+64) as 2x4 tiles of 16x16 MFMA.
__device__ __forceinline__ void load_lds16(const void* g, void* l) {
  __builtin_amdgcn_global_load_lds(
      (const __attribute__((address_space(1))) unsigned int*)g,
      (__attribute__((address_space(3))) unsigned int*)l, 16, 0, 0);
}

template <typename AT, int K>
__global__ __launch_bounds__(256, 4) void k_gemm_mfma(
    const AT* __restrict__ X, const __bf16* __restrict__ Bt,
    const float* __restrict__ br, __bf16* __restrict__ XW,
    float* __restrict__ RES, int M) {
  __shared__ alignas(16) __bf16 As[32 * 72];   // [row][k], padded stride 72
  __shared__ alignas(16) __bf16 Bs[256 * 64];  // [n][k], XOR-swizzled 16B chunks; reused as f32 Cb[32][256]
  const int tid = threadIdx.x;
  const int lane = tid & 63;
  const int w = tid >> 6;
  const int l15 = lane & 15;
  const int quad = lane >> 4;
  const int bm0 = blockIdx.x * 32;

  const int arow = tid >> 3;       // 0..31
  const int akq = (tid & 7) << 3;  // k elem 0..56
  int agrow = bm0 + arow; if (agrow > M - 1) agrow = M - 1;
  const AT* aptr = X + (size_t)agrow * K + akq;

  floatx4 acc[2][4];
#pragma unroll
  for (int i = 0; i < 2; ++i)
#pragma unroll
    for (int j = 0; j < 4; ++j) acc[i][j] = (floatx4)0.f;

  for (int k0 = 0; k0 < K; k0 += 64) {
    // --- stage A (32x64) ---
    if constexpr (sizeof(AT) == 4) {
      const float4 u = *(const float4*)(aptr + k0);
      const float4 v = *(const float4*)(aptr + k0 + 4);
      bf16x8 h;
      h[0] = (__bf16)u.x; h[1] = (__bf16)u.y; h[2] = (__bf16)u.z; h[3] = (__bf16)u.w;
      h[4] = (__bf16)v.x; h[5] = (__bf16)v.y; h[6] = (__bf16)v.z; h[7] = (__bf16)v.w;
      *(bf16x8*)&As[arow * 72 + akq] = h;
    } else {
      *(bf16x8*)&As[arow * 72 + akq] = *(const bf16x8*)(aptr + k0);
    }
    // --- stage B (256x64) via global_load_lds, 8 issues/wave, XOR chunk swizzle ---
#pragma unroll
    for (int ii = 0; ii < 8; ++ii) {
      const int wi = ii * 4 + w;            // 0..31 -> dst Bs + wi*1024
      const int n = wi * 8 + (lane >> 3);   // 0..255
      const int c = lane & 7;               // dst 16B chunk in row
      const int cs = c ^ (n & 7);           // src chunk (bank swizzle)
      const char* g = (const char*)Bt + (size_t)n * (K * 2) + (size_t)k0 * 2 + cs * 16;
      load_lds16(g, (char*)Bs + wi * 1024);
    }
    __syncthreads();
    // --- fragments + MFMA ---
    bf16x8 af[2][2], bfr[4][2];
#pragma unroll
    for (int mt = 0; mt < 2; ++mt)
#pragma unroll
      for (int ks = 0; ks < 2; ++ks)
        af[mt][ks] = *(const bf16x8*)&As[(mt * 16 + l15) * 72 + ks * 32 + quad * 8];
#pragma unroll
    for (int nt = 0; nt < 4; ++nt) {
      const int n = w * 64 + nt * 16 + l15;
#pragma unroll
      for (int ks = 0; ks < 2; ++ks) {
        const int ch = (ks * 4 + quad) ^ (n & 7);
        bfr[nt][ks] = *(const bf16x8*)&Bs[n * 64 + ch * 8];
      }
    }
#pragma unroll
    for (int ks = 0; ks < 2; ++ks)
#pragma unroll
      for (int mt = 0; mt < 2; ++mt)
#pragma unroll
        for (int nt = 0; nt < 4; ++nt)
          acc[mt][nt] = __builtin_amdgcn_mfma_f32_16x16x32_bf16(af[mt][ks], bfr[nt][ks],
                                                                acc[mt][nt], 0, 0, 0);
    __syncthreads();
  }

  // --- epilogue via LDS transpose (Bs reused as f32 Cb[32][256]) ---
  float* Cb = (float*)Bs;
#pragma unroll
  for (int mt = 0; mt < 2; ++mt)
#pragma unroll
    for (int nt = 0; nt < 4; ++nt)
#pragma unroll
      for (int r = 0; r < 4; ++r)
        Cb[(mt * 16 + quad * 4 + r) * 256 + (w * 64 + nt * 16 + l15)] = acc[mt][nt][r];
  __syncthreads();
  const int row = tid >> 3;
  const int seg = tid & 7;
  const int grow = bm0 + row;
  if (grow < M) {
    if (seg < 4) {  // XW cols seg*32..+31 -> bf16
      const int c0 = seg * 32;
#pragma unroll
      for (int j = 0; j < 4; ++j) {
        const float4 v0 = *(const float4*)&Cb[row * 256 + c0 + j * 8];
        const float4 v1 = *(const float4*)&Cb[row * 256 + c0 + j * 8 + 4];
        bf16x8 h;
        h[0] = (__bf16)v0.x; h[1] = (__bf16)v0.y; h[2] = (__bf16)v0.z; h[3] = (__bf16)v0.w;
        h[4] = (__bf16)v1.x; h[5] = (__bf16)v1.y; h[6] = (__bf16)v1.z; h[7] = (__bf16)v1.w;
        *(bf16x8*)&XW[(size_t)grow * DH + c0 + j * 8] = h;
      }
    } else {  // RES cols (seg-4)*32..+31 -> relu(x+br) f32
      const int c0 = (seg - 4) * 32;
#pragma unroll
      for (int j = 0; j < 8; ++j) {
        const float4 v = *(const float4*)&Cb[row * 256 + 128 + c0 + j * 4];
        const float4 bb = *(const float4*)&br[c0 + j * 4];
        *(float4*)&RES[(size_t)grow * DH + c0 + j * 4] =
            make_float4(fmaxf(v.x + bb.x, 0.f), fmaxf(v.y + bb.y, 0.f),
                        fmaxf(v.z + bb.z, 0.f), fmaxf(v.w + bb.w, 0.f));
      }
    }
  }
}

// ---------------- aggregation + bias + relu + residual + BN (+ fused head) ----------------
// one wave per node; lane handles feature pair (2*lane, 2*lane+1).
// MODE 0: write h as bf16 pairs. MODE 1: fused head -> softmax out.
template <int MODE>
__global__ __launch_bounds__(256) void k_agg2(
    const __bf16* __restrict__ XW, const float* __restrict__ RES,
    const int* __restrict__ row_ptr, const int* __restrict__ csr_src,
    const float* __restrict__ b, const float* __restrict__ gamma,
    const float* __restrict__ beta, const float* __restrict__ mean,
    const float* __restrict__ var, const float* __restrict__ Wd,
    const float* __restrict__ bd, void* __restrict__ hout, int M) {
  const int node = (blockIdx.x << 2) + (threadIdx.x >> 6);
  const int lane = threadIdx.x & 63;
  if (node >= M) return;
  const int s = row_ptr[node], e = row_ptr[node + 1];
  const unsigned* xw = (const unsigned*)XW;  // 64 uints per row = 128 bf16
  float ax = 0.f, ay = 0.f;
  int i = s;
  for (; i + 3 < e; i += 4) {
    const int s0 = csr_src[i], s1 = csr_src[i + 1], s2 = csr_src[i + 2], s3 = csr_src[i + 3];
    const unsigned u0 = xw[(size_t)s0 * 64 + lane];
    const unsigned u1 = xw[(size_t)s1 * 64 + lane];
    const unsigned u2 = xw[(size_t)s2 * 64 + lane];
    const unsigned u3 = xw[(size_t)s3 * 64 + lane];
    ax += __uint_as_float(u0 << 16) + __uint_as_float(u1 << 16) +
          __uint_as_float(u2 << 16) + __uint_as_float(u3 << 16);
    ay += __uint_as_float(u0 & 0xffff0000u) + __uint_as_float(u1 & 0xffff0000u) +
          __uint_as_float(u2 & 0xffff0000u) + __uint_as_float(u3 & 0xffff0000u);
  }
  for (; i < e; ++i) {
    const unsigned u = xw[(size_t)csr_src[i] * 64 + lane];
    ax += __uint_as_float(u << 16);
    ay += __uint_as_float(u & 0xffff0000u);
  }
  const int f0 = lane << 1;
  const float2 bb = *(const float2*)&b[f0];
  const float2 rr = *(const float2*)&RES[(size_t)node * DH + f0];
  const float2 mm = *(const float2*)&mean[f0];
  const float2 vv = *(const float2*)&var[f0];
  const float2 gg = *(const float2*)&gamma[f0];
  const float2 be = *(const float2*)&beta[f0];
  const float x0 = fmaxf(ax + bb.x, 0.f) + rr.x;
  const float x1 = fmaxf(ay + bb.y, 0.f) + rr.y;
  const float y0 = (x0 - mm.x) * rsqrtf(vv.x + 1e-5f) * gg.x + be.x;
  const float y1 = (x1 - mm.y) * rsqrtf(vv.y + 1e-5f) * gg.y + be.y;
  if (MODE == 0) {
    union { __bf16 h[2]; unsigned u; } pk;
    pk.h[0] = (__bf16)y0;
    pk.h[1] = (__bf16)y1;
    ((unsigned*)hout)[(size_t)node * 64 + lane] = pk.u;
  } else {
    const float4 wv = *(const float4*)&Wd[f0 * 2];  // Wd[f0][0,1], Wd[f0+1][0,1]
    float l0 = y0 * wv.x + y1 * wv.z;
    float l1 = y0 * wv.y + y1 * wv.w;
#pragma unroll
    for (int off = 32; off > 0; off >>= 1) {
      l0 += __shfl_down(l0, off);
      l1 += __shfl_down(l1, off);
    }
    if (lane == 0) {
      l0 += bd[0];
      l1 += bd[1];
      const float m = fmaxf(l0, l1);
      const float e0 = expf(l0 - m), e1 = expf(l1 - m);
      const float inv = 1.f / (e0 + e1);
      float* out = (float*)hout;
      out[(size_t)node * 2] = e0 * inv;
      out[(size_t)node * 2 + 1] = e1 * inv;
    }
  }
}

// ---------------- launch ----------------
extern "C" void kernel_launch(void* const* d_in, const int* in_sizes, int n_in,
                              void* d_out, int out_size, void* d_ws, size_t ws_size,
                              hipStream_t stream) {
  const float* in_feat = (const float*)d_in[0];
  const int* src = (const int*)d_in[1];
  const int* dst = (const int*)d_in[2];
  const float* W0 = (const float*)d_in[3];
  const float* b0 = (const float*)d_in[4];
  const float* Wr0 = (const float*)d_in[5];
  const float* br0 = (const float*)d_in[6];
  const float* gamma0 = (const float*)d_in[7];
  const float* beta0 = (const float*)d_in[8];
  const float* mean0 = (const float*)d_in[9];
  const float* var0 = (const float*)d_in[10];
  const float* W1 = (const float*)d_in[11];
  const float* b1 = (const float*)d_in[12];
  const float* Wr1 = (const float*)d_in[13];
  const float* br1 = (const float*)d_in[14];
  const float* gamma1 = (const float*)d_in[15];
  const float* beta1 = (const float*)d_in[16];
  const float* mean1 = (const float*)d_in[17];
  const float* var1 = (const float*)d_in[18];
  const float* Wd = (const float*)d_in[19];
  const float* bd = (const float*)d_in[20];
  float* out = (float*)d_out;

  char* ws = (char*)d_ws;
  size_t off = 0;
  auto alloc = [&](size_t bytes) {
    void* p = ws + off;
    off += (bytes + 255) & ~(size_t)255;
    return p;
  };
  __bf16* XWb = (__bf16*)alloc(sizeof(__bf16) * (size_t)NNODES * DH);  // 12.8 MB
  __bf16* h1 = (__bf16*)alloc(sizeof(__bf16) * (size_t)NNODES * DH);   // 12.8 MB
  float* RES = (float*)alloc(sizeof(float) * (size_t)NNODES * DH);     // 25.6 MB
  int* cnt = (int*)alloc(sizeof(int) * NNODES);
  int* cursor = (int*)alloc(sizeof(int) * NNODES);
  int* row_ptr = (int*)alloc(sizeof(int) * (NNODES + 1));
  int* csr_src = (int*)alloc(sizeof(int) * NEDGES);
  int* bsum = (int*)alloc(sizeof(int) * 64);
  int* boff = (int*)alloc(sizeof(int) * 64);
  __bf16* Bt0 = (__bf16*)alloc(sizeof(__bf16) * 256 * KIN);
  __bf16* Bt1 = (__bf16*)alloc(sizeof(__bf16) * 256 * DH);

  const int nb = (NNODES + 1023) / 1024;  // 49
  // CSR build
  k_zero2<<<(NNODES + 255) / 256, 256, 0, stream>>>(cnt, cursor, NNODES);
  k_hist<<<(NEDGES + 255) / 256, 256, 0, stream>>>(dst, cnt, NEDGES);
  k_scan_local<<<nb, 1024, 0, stream>>>(cnt, row_ptr, bsum, NNODES);
  k_scan_sums<<<1, 64, 0, stream>>>(bsum, boff, nb, row_ptr, NNODES);
  k_scan_add<<<(NNODES + 255) / 256, 256, 0, stream>>>(row_ptr, boff, NNODES);
  k_fill<<<(NEDGES + 255) / 256, 256, 0, stream>>>(src, dst, row_ptr, cursor, csr_src, NEDGES);

  // weight pre-convert
  k_prepB<<<KIN, 256, 0, stream>>>(W0, Wr0, Bt0, KIN, 10);
  k_prepB<<<DH, 256, 0, stream>>>(W1, Wr1, Bt1, DH, 7);

  const int ggrid = (NNODES + 31) / 32;
  const int agrid = (NNODES + 3) / 4;
  // layer 0
  k_gemm_mfma<float, KIN><<<ggrid, 256, 0, stream>>>(in_feat, Bt0, br0, XWb, RES, NNODES);
  k_agg2<0><<<agrid, 256, 0, stream>>>(XWb, RES, row_ptr, csr_src, b0, gamma0, beta0,
                                       mean0, var0, nullptr, nullptr, h1, NNODES);
  // layer 1 (+ fused head)
  k_gemm_mfma<__bf16, DH><<<ggrid, 256, 0, stream>>>(h1, Bt1, br1, XWb, RES, NNODES);
  k_agg2<1><<<agrid, 256, 0, stream>>>(XWb, RES, row_ptr, csr_src, b1, gamma1, beta1,
                                       mean1, var1, Wd, bd, out, NNODES);
}